// Round 8
// baseline (67192.383 us; speedup 1.0000x reference)
//
#include <hip/hip_runtime.h>
#include <hip/hip_fp16.h>

typedef unsigned int u32;

#define BATCH 256
#define TSTEPS 1024
#define HDIM 256
#define ODIM 32

// ---------------- workspace layout (bytes) ----------------
// blob : u32 [512][216]  per-thread reg weights (mr 64 | mz 64 | mhn 64 | obs 24)
// mxnL : uint4[16][512]  lane-major M_xn   (131072 B)
// woL  : uint4[ 2][512]  lane-major W_out  (16384 B)   (contiguous after mxnL)
// cvec/cvec0: f32 [256][3][256]
#define OFF_BLOB  0u
#define OFF_MXN   442368u
#define OFF_WO    573440u
#define OFF_CVEC  589824u
#define OFF_CVEC0 1376256u
// total 2162688

static __device__ __forceinline__ u32 packh2(float a, float b) {
  __half2 h = __floats2half2_rn(a, b);
  return *reinterpret_cast<u32*>(&h);
}
static __device__ __forceinline__ float mac2(float acc, u32 w, float h0, float h1) {
  const __half2 hh = *reinterpret_cast<const __half2*>(&w);
  const float2 f = __half22float2(hh);
  acc = fmaf(f.x, h0, acc);
  acc = fmaf(f.y, h1, acc);
  return acc;
}

// ---------------------------------------------------------------------------
// k_pack: per-thread register blobs + lane-major LDS images of M_xn / W_out.
//   thread tid = 2*j + s  (j = hidden unit, s = 128-elem h half)
//   M_r = W_hh_r + W_ihy_r*W_out ; M_z likewise ; M_hn = W_hh_n ;
//   M_xn = W_ihy_n*W_out (fold of y-feedback through the n-gate)
// grid 2 x 256
// ---------------------------------------------------------------------------
__global__ void k_pack(const float* __restrict__ W_ih, const float* __restrict__ W_hh,
                       const float* __restrict__ W_out, u32* __restrict__ blob,
                       uint4* __restrict__ mxnL, uint4* __restrict__ woL) {
  const int tid = blockIdx.x * 256 + threadIdx.x;  // 0..511
  const int j = tid >> 1, s = tid & 1;
  const int e0 = 128 * s;
  u32* bb = blob + tid * 216;

  for (int k = 0; k < 16; ++k) {
    float vr[8], vz[8], vh[8], vx[8];
#pragma unroll
    for (int q = 0; q < 8; ++q) {
      const int e = e0 + 8 * k + q;
      vr[q] = W_hh[(j)       * HDIM + e];
      vz[q] = W_hh[(256 + j) * HDIM + e];
      vh[q] = W_hh[(512 + j) * HDIM + e];
      vx[q] = 0.f;
    }
#pragma unroll 8
    for (int u = 0; u < 32; ++u) {
      const float ar = W_ih[(j)       * 96 + 32 + u];
      const float az = W_ih[(256 + j) * 96 + 32 + u];
      const float an = W_ih[(512 + j) * 96 + 32 + u];
#pragma unroll
      for (int q = 0; q < 8; ++q) {
        const float wo = W_out[u * HDIM + e0 + 8 * k + q];
        vr[q] = fmaf(ar, wo, vr[q]);
        vz[q] = fmaf(az, wo, vz[q]);
        vx[q] = fmaf(an, wo, vx[q]);
      }
    }
#pragma unroll
    for (int i = 0; i < 4; ++i) {
      bb[      4 * k + i] = packh2(vr[2 * i], vr[2 * i + 1]);
      bb[64  + 4 * k + i] = packh2(vz[2 * i], vz[2 * i + 1]);
      bb[128 + 4 * k + i] = packh2(vh[2 * i], vh[2 * i + 1]);
    }
    uint4 xq;
    xq.x = packh2(vx[0], vx[1]); xq.y = packh2(vx[2], vx[3]);
    xq.z = packh2(vx[4], vx[5]); xq.w = packh2(vx[6], vx[7]);
    mxnL[k * 512 + tid] = xq;
  }
  // obs-weight fragments: gate g, obs elems 16s .. 16s+15
#pragma unroll
  for (int g = 0; g < 3; ++g)
#pragma unroll
    for (int i = 0; i < 8; ++i)
      bb[192 + 8 * g + i] = packh2(W_ih[(g * 256 + j) * 96 + 16 * s + 2 * i],
                                   W_ih[(g * 256 + j) * 96 + 16 * s + 2 * i + 1]);
  // W_out lane-major: thread (o = tid&31, c = tid>>5) covers h[16c..16c+15]
  {
    const int o = tid & 31, c = tid >> 5;
#pragma unroll
    for (int i = 0; i < 2; ++i) {
      uint4 wq;
      wq.x = packh2(W_out[o * HDIM + 16 * c + 8 * i],     W_out[o * HDIM + 16 * c + 8 * i + 1]);
      wq.y = packh2(W_out[o * HDIM + 16 * c + 8 * i + 2], W_out[o * HDIM + 16 * c + 8 * i + 3]);
      wq.z = packh2(W_out[o * HDIM + 16 * c + 8 * i + 4], W_out[o * HDIM + 16 * c + 8 * i + 5]);
      wq.w = packh2(W_out[o * HDIM + 16 * c + 8 * i + 6], W_out[o * HDIM + 16 * c + 8 * i + 7]);
      woL[i * 512 + tid] = wq;
    }
  }
}

// ---------------------------------------------------------------------------
// k_cvec: per-batch constants (r/z/xn), steady-state and t==0 variants.
// ---------------------------------------------------------------------------
__global__ void k_cvec(const float* __restrict__ W_ih, const float* __restrict__ b_ih,
                       const float* __restrict__ b_hh, const float* __restrict__ b_out,
                       const float* __restrict__ z_dyn, const float* __restrict__ init_y,
                       float* __restrict__ cvec, float* __restrict__ cvec0) {
  const int b = blockIdx.x, j = threadIdx.x;
  __shared__ float zs[32], bo[32], y0[32];
  if (j < 32) {
    zs[j] = z_dyn[b * 32 + j];
    bo[j] = b_out[j];
    y0[j] = init_y[b * 32 + j];
  }
  __syncthreads();
#pragma unroll
  for (int q = 0; q < 3; ++q) {
    const int g = q * 256 + j;
    const float base = b_ih[g] + ((q < 2) ? b_hh[g] : 0.f);
    float zd = 0.f, yd = 0.f, y0d = 0.f;
#pragma unroll 8
    for (int u = 0; u < 32; ++u) {
      const float wz = W_ih[g * 96 + 64 + u];
      const float wy = W_ih[g * 96 + 32 + u];
      zd  = fmaf(wz, zs[u], zd);
      yd  = fmaf(wy, bo[u], yd);
      y0d = fmaf(wy, y0[u], y0d);
    }
    cvec [(b * 3 + q) * 256 + j] = base + zd + yd;
    cvec0[(b * 3 + q) * 256 + j] = base + zd + y0d;
  }
}

// ---------------------------------------------------------------------------
// Main persistent GRU. grid 256 (batch), block 512.
// REGISTER BUDGET: the backend's occupancy heuristic granted 65536/T VGPRs
// in R1/R2/R3/R6 (T=512 -> 128) and ignored both launch_bounds' 2nd arg and
// amdgpu_waves_per_eu — likely because dynamic LDS is invisible at compile
// time. amdgpu_num_vgpr(256) REPLACES the heuristic-derived cap per LLVM
// AMDGPUUsage (amdgpu-num-vgpr). 8 waves x 256 VGPR = full 2048-reg file,
// hardware-valid (m69: 8 waves/CU @ 256 regs).
// Weight regs 216 + ~30 live <= 256. Gate constants in LDS (cv_s).
// h_s padded [2][132] -> bank conflicts measured 0 (R6).
// LDS: mxn 131072 | wo 16384 | h 1056 | x 256 | yp 4096 | cv 6144 = 159008 B
// ---------------------------------------------------------------------------
#define LDS_MXN 0
#define LDS_WO  131072
#define LDS_H   147456
#define LDS_X   148512
#define LDS_YP  148768
#define LDS_CV  152864
#define LDS_BYTES 159008

__attribute__((amdgpu_waves_per_eu(2, 2), amdgpu_num_vgpr(256)))
__global__ __launch_bounds__(512) void k_gru(
    const float* __restrict__ obs, const u32* __restrict__ blob,
    const uint4* __restrict__ matsrc,  // = ws+OFF_MXN (mxnL||woL contiguous)
    const float* __restrict__ cvec, const float* __restrict__ cvec0,
    const float* __restrict__ b_hh, const float* __restrict__ b_out,
    float* __restrict__ out) {
  extern __shared__ char smem[];
  uint4* mxn_s = reinterpret_cast<uint4*>(smem + LDS_MXN);  // [16][512]
  uint4* wo_s  = reinterpret_cast<uint4*>(smem + LDS_WO);   // [2][512]
  float* h_s   = reinterpret_cast<float*>(smem + LDS_H);    // [2][132] padded
  float* x_s   = reinterpret_cast<float*>(smem + LDS_X);    // [2][32]
  float* yp_s  = reinterpret_cast<float*>(smem + LDS_YP);   // [2][16][32]
  float* cv_s  = reinterpret_cast<float*>(smem + LDS_CV);   // [2][3][256]

  const int b = blockIdx.x;
  const int tid = threadIdx.x;
  const int j = tid >> 1, s = tid & 1;
  const int o = tid & 31, c = tid >> 5;

  // ---- stage mxnL || woL into LDS (one contiguous 147456-B copy) ----
  {
    uint4* dst = reinterpret_cast<uint4*>(smem);
    for (int i = tid; i < 9216; i += 512) dst[i] = matsrc[i];
  }
  // ---- stage gate constants: cv_s[0]=cvec0 (t==0), cv_s[1]=cvec (t>0) ----
  for (int i = tid; i < 768; i += 512) {
    cv_s[i]       = cvec0[b * 768 + i];
    cv_s[768 + i] = cvec [b * 768 + i];
  }

  // ---- per-thread weight regs: 216 u32 (54 uint4) ----
  u32 wb[216];
  {
    const uint4* src = reinterpret_cast<const uint4*>(blob + tid * 216);
#pragma unroll
    for (int i = 0; i < 54; ++i) {
      const uint4 v = src[i];
      wb[4 * i] = v.x; wb[4 * i + 1] = v.y; wb[4 * i + 2] = v.z; wb[4 * i + 3] = v.w;
    }
  }

  const float chn = b_hh[512 + j];
  const float bo  = (tid < 32) ? b_out[tid] : 0.f;

  const float* obs_b = obs + (size_t)b * TSTEPS * 32;
  float* out_b = out + (size_t)b * TSTEPS * 32;

  const int hb = 132 * s;  // my padded h slice base (f32 units)

  float hreg = 0.f;
  if (tid < 256) h_s[(tid >> 7) * 132 + (tid & 127)] = 0.f;
  if (tid < 32) x_s[tid] = obs_b[tid];
  __syncthreads();

#pragma unroll 1
  for (int t = 0; t < TSTEPS; ++t) {
    const int cur = t & 1;
    // next-obs prefetch by threads 32..63 (disjoint from y-finalize threads)
    float pf = 0.f;
    if (tid >= 32 && tid < 64) pf = obs_b[(t < TSTEPS - 1 ? t + 1 : t) * 32 + (tid - 32)];

    // gate constants from LDS (issued early; latency hidden under MACs)
    const int tb = (t != 0) ? 768 : 0;
    const float cr  = cv_s[tb + j];
    const float cz  = cv_s[tb + 256 + j];
    const float cxn = cv_s[tb + 512 + j];

    float aR = 0.f, aZ = 0.f, aXN = 0.f, aHN = 0.f;
#pragma unroll
    for (int k = 0; k < 16; ++k) {
      const float4 ha = *reinterpret_cast<const float4*>(&h_s[hb + 8 * k]);
      const float4 hc = *reinterpret_cast<const float4*>(&h_s[hb + 8 * k + 4]);
      const uint4  xw = mxn_s[k * 512 + tid];
      aR  = mac2(aR,  wb[      4 * k],     ha.x, ha.y);
      aR  = mac2(aR,  wb[      4 * k + 1], ha.z, ha.w);
      aR  = mac2(aR,  wb[      4 * k + 2], hc.x, hc.y);
      aR  = mac2(aR,  wb[      4 * k + 3], hc.z, hc.w);
      aZ  = mac2(aZ,  wb[64  + 4 * k],     ha.x, ha.y);
      aZ  = mac2(aZ,  wb[64  + 4 * k + 1], ha.z, ha.w);
      aZ  = mac2(aZ,  wb[64  + 4 * k + 2], hc.x, hc.y);
      aZ  = mac2(aZ,  wb[64  + 4 * k + 3], hc.z, hc.w);
      aHN = mac2(aHN, wb[128 + 4 * k],     ha.x, ha.y);
      aHN = mac2(aHN, wb[128 + 4 * k + 1], ha.z, ha.w);
      aHN = mac2(aHN, wb[128 + 4 * k + 2], hc.x, hc.y);
      aHN = mac2(aHN, wb[128 + 4 * k + 3], hc.z, hc.w);
      aXN = mac2(aXN, xw.x, ha.x, ha.y);
      aXN = mac2(aXN, xw.y, ha.z, ha.w);
      aXN = mac2(aXN, xw.z, hc.x, hc.y);
      aXN = mac2(aXN, xw.w, hc.z, hc.w);
    }
#pragma unroll
    for (int i = 0; i < 4; ++i) {
      const float4 xv = *reinterpret_cast<const float4*>(&x_s[cur * 32 + 16 * s + 4 * i]);
      aR  = mac2(aR,  wb[192 + 2 * i],     xv.x, xv.y);
      aR  = mac2(aR,  wb[192 + 2 * i + 1], xv.z, xv.w);
      aZ  = mac2(aZ,  wb[200 + 2 * i],     xv.x, xv.y);
      aZ  = mac2(aZ,  wb[200 + 2 * i + 1], xv.z, xv.w);
      aXN = mac2(aXN, wb[208 + 2 * i],     xv.x, xv.y);
      aXN = mac2(aXN, wb[208 + 2 * i + 1], xv.z, xv.w);
    }

    // pair reduction (threads 2j, 2j+1 — same wave)
    aR  += __shfl_xor(aR,  1);
    aZ  += __shfl_xor(aZ,  1);
    aHN += __shfl_xor(aHN, 1);
    aXN += __shfl_xor(aXN, 1);

    const float r    = 1.f / (1.f + __expf(-(cr + aR)));
    const float zg   = 1.f / (1.f + __expf(-(cz + aZ)));
    const float pn   = cxn + aXN + r * (chn + aHN);
    const float n    = 1.f - 2.f / (1.f + __expf(2.f * pn));  // tanh
    const float hnew = fmaf(zg, hreg - n, n);
    hreg = hnew;

    __syncthreads();  // A: all reads of h_s / x_s[cur] done
    if (s == 0) h_s[(j >> 7) * 132 + (j & 127)] = hnew;
    if (tid >= 32 && tid < 64) x_s[(1 - cur) * 32 + (tid - 32)] = pf;
    if (t > 0 && tid < 32) {  // finalize y_{t-1}
      float y = bo;
#pragma unroll
      for (int ww = 0; ww < 16; ++ww) y += yp_s[(1 - cur) * 512 + ww * 32 + tid];
      out_b[(t - 1) * 32 + tid] = y;
    }
    __syncthreads();  // B: new h visible

    // y partials for h_t: thread (o, c) covers h[16c..16c+15]
    {
      const int hy = (c >> 3) * 132 + (c & 7) * 16;
      const float4 h0 = *reinterpret_cast<const float4*>(&h_s[hy]);
      const float4 h1 = *reinterpret_cast<const float4*>(&h_s[hy + 4]);
      const float4 h2 = *reinterpret_cast<const float4*>(&h_s[hy + 8]);
      const float4 h3 = *reinterpret_cast<const float4*>(&h_s[hy + 12]);
      const uint4 w0 = wo_s[tid];
      const uint4 w1 = wo_s[512 + tid];
      float yv = 0.f;
      yv = mac2(yv, w0.x, h0.x, h0.y); yv = mac2(yv, w0.y, h0.z, h0.w);
      yv = mac2(yv, w0.z, h1.x, h1.y); yv = mac2(yv, w0.w, h1.z, h1.w);
      yv = mac2(yv, w1.x, h2.x, h2.y); yv = mac2(yv, w1.y, h2.z, h2.w);
      yv = mac2(yv, w1.z, h3.x, h3.y); yv = mac2(yv, w1.w, h3.z, h3.w);
      yp_s[cur * 512 + c * 32 + o] = yv;
    }
  }

  __syncthreads();
  if (tid < 32) {  // flush y_1023 (t=1023 -> cur=1)
    float y = bo;
#pragma unroll
    for (int ww = 0; ww < 16; ++ww) y += yp_s[512 + ww * 32 + tid];
    out_b[(TSTEPS - 1) * 32 + tid] = y;
  }
}

// ---------------------------------------------------------------------------
extern "C" void kernel_launch(void* const* d_in, const int* in_sizes, int n_in,
                              void* d_out, int out_size, void* d_ws, size_t ws_size,
                              hipStream_t stream) {
  (void)in_sizes; (void)n_in; (void)out_size; (void)ws_size;
  const float* init_y  = (const float*)d_in[0];
  const float* obs_seq = (const float*)d_in[1];
  const float* z_dyn   = (const float*)d_in[2];
  const float* W_ih    = (const float*)d_in[3];
  const float* W_hh    = (const float*)d_in[4];
  const float* b_ih    = (const float*)d_in[5];
  const float* b_hh    = (const float*)d_in[6];
  const float* W_out   = (const float*)d_in[7];
  const float* b_out   = (const float*)d_in[8];
  float* out = (float*)d_out;

  char* ws = (char*)d_ws;
  u32*   blob  = (u32*)(ws + OFF_BLOB);
  uint4* mxnL  = (uint4*)(ws + OFF_MXN);
  uint4* woL   = (uint4*)(ws + OFF_WO);
  float* cvec  = (float*)(ws + OFF_CVEC);
  float* cvec0 = (float*)(ws + OFF_CVEC0);

  hipFuncSetAttribute((const void*)k_gru,
                      hipFuncAttributeMaxDynamicSharedMemorySize, LDS_BYTES);

  k_pack<<<2, 256, 0, stream>>>(W_ih, W_hh, W_out, blob, mxnL, woL);
  k_cvec<<<256, 256, 0, stream>>>(W_ih, b_ih, b_hh, b_out, z_dyn, init_y, cvec, cvec0);
  k_gru<<<BATCH, 512, LDS_BYTES, stream>>>(obs_seq, blob, (const uint4*)(ws + OFF_MXN),
                                           cvec, cvec0, b_hh, b_out, out);
}

// Round 9
// 28844.653 us; speedup vs baseline: 2.3295x; 2.3295x over previous
//
#include <hip/hip_runtime.h>
#include <hip/hip_fp16.h>

typedef unsigned int u32;

#define BATCH 256
#define TSTEPS 1024
#define HDIM 256
#define ODIM 32

// ---------------- workspace layout (bytes) ----------------
// blob : u32 [512][216]  per-thread weights (mr 64 | mz 64 | mhn 64 | obs 24)
// mxnL : uint4[16][512]  lane-major M_xn   (131072 B)
// woL  : uint4[ 2][512]  lane-major W_out  (16384 B)   (contiguous after mxnL)
// cvec/cvec0: f32 [256][3][256]
#define OFF_BLOB  0u
#define OFF_MXN   442368u
#define OFF_WO    573440u
#define OFF_CVEC  589824u
#define OFF_CVEC0 1376256u
// total 2162688

static __device__ __forceinline__ u32 packh2(float a, float b) {
  __half2 h = __floats2half2_rn(a, b);
  return *reinterpret_cast<u32*>(&h);
}
static __device__ __forceinline__ float mac2(float acc, u32 w, float h0, float h1) {
  const __half2 hh = *reinterpret_cast<const __half2*>(&w);
  const float2 f = __half22float2(hh);
  acc = fmaf(f.x, h0, acc);
  acc = fmaf(f.y, h1, acc);
  return acc;
}

// ---------------------------------------------------------------------------
// k_pack: per-thread weight blobs + lane-major LDS images of M_xn / W_out.
//   thread tid = 2*j + s  (j = hidden unit, s = 128-elem h half)
//   M_r = W_hh_r + W_ihy_r*W_out ; M_z likewise ; M_hn = W_hh_n ;
//   M_xn = W_ihy_n*W_out (fold of y-feedback through the n-gate)
// grid 2 x 256
// ---------------------------------------------------------------------------
__global__ void k_pack(const float* __restrict__ W_ih, const float* __restrict__ W_hh,
                       const float* __restrict__ W_out, u32* __restrict__ blob,
                       uint4* __restrict__ mxnL, uint4* __restrict__ woL) {
  const int tid = blockIdx.x * 256 + threadIdx.x;  // 0..511
  const int j = tid >> 1, s = tid & 1;
  const int e0 = 128 * s;
  u32* bb = blob + tid * 216;

  for (int k = 0; k < 16; ++k) {
    float vr[8], vz[8], vh[8], vx[8];
#pragma unroll
    for (int q = 0; q < 8; ++q) {
      const int e = e0 + 8 * k + q;
      vr[q] = W_hh[(j)       * HDIM + e];
      vz[q] = W_hh[(256 + j) * HDIM + e];
      vh[q] = W_hh[(512 + j) * HDIM + e];
      vx[q] = 0.f;
    }
#pragma unroll 8
    for (int u = 0; u < 32; ++u) {
      const float ar = W_ih[(j)       * 96 + 32 + u];
      const float az = W_ih[(256 + j) * 96 + 32 + u];
      const float an = W_ih[(512 + j) * 96 + 32 + u];
#pragma unroll
      for (int q = 0; q < 8; ++q) {
        const float wo = W_out[u * HDIM + e0 + 8 * k + q];
        vr[q] = fmaf(ar, wo, vr[q]);
        vz[q] = fmaf(az, wo, vz[q]);
        vx[q] = fmaf(an, wo, vx[q]);
      }
    }
#pragma unroll
    for (int i = 0; i < 4; ++i) {
      bb[      4 * k + i] = packh2(vr[2 * i], vr[2 * i + 1]);
      bb[64  + 4 * k + i] = packh2(vz[2 * i], vz[2 * i + 1]);
      bb[128 + 4 * k + i] = packh2(vh[2 * i], vh[2 * i + 1]);
    }
    uint4 xq;
    xq.x = packh2(vx[0], vx[1]); xq.y = packh2(vx[2], vx[3]);
    xq.z = packh2(vx[4], vx[5]); xq.w = packh2(vx[6], vx[7]);
    mxnL[k * 512 + tid] = xq;
  }
  // obs-weight fragments: gate g, obs elems 16s .. 16s+15
#pragma unroll
  for (int g = 0; g < 3; ++g)
#pragma unroll
    for (int i = 0; i < 8; ++i)
      bb[192 + 8 * g + i] = packh2(W_ih[(g * 256 + j) * 96 + 16 * s + 2 * i],
                                   W_ih[(g * 256 + j) * 96 + 16 * s + 2 * i + 1]);
  // W_out lane-major: thread (o = tid&31, c = tid>>5) covers h[16c..16c+15]
  {
    const int o = tid & 31, c = tid >> 5;
#pragma unroll
    for (int i = 0; i < 2; ++i) {
      uint4 wq;
      wq.x = packh2(W_out[o * HDIM + 16 * c + 8 * i],     W_out[o * HDIM + 16 * c + 8 * i + 1]);
      wq.y = packh2(W_out[o * HDIM + 16 * c + 8 * i + 2], W_out[o * HDIM + 16 * c + 8 * i + 3]);
      wq.z = packh2(W_out[o * HDIM + 16 * c + 8 * i + 4], W_out[o * HDIM + 16 * c + 8 * i + 5]);
      wq.w = packh2(W_out[o * HDIM + 16 * c + 8 * i + 6], W_out[o * HDIM + 16 * c + 8 * i + 7]);
      woL[i * 512 + tid] = wq;
    }
  }
}

// ---------------------------------------------------------------------------
// k_cvec: per-batch constants (r/z/xn), steady-state and t==0 variants.
// ---------------------------------------------------------------------------
__global__ void k_cvec(const float* __restrict__ W_ih, const float* __restrict__ b_ih,
                       const float* __restrict__ b_hh, const float* __restrict__ b_out,
                       const float* __restrict__ z_dyn, const float* __restrict__ init_y,
                       float* __restrict__ cvec, float* __restrict__ cvec0) {
  const int b = blockIdx.x, j = threadIdx.x;
  __shared__ float zs[32], bo[32], y0[32];
  if (j < 32) {
    zs[j] = z_dyn[b * 32 + j];
    bo[j] = b_out[j];
    y0[j] = init_y[b * 32 + j];
  }
  __syncthreads();
#pragma unroll
  for (int q = 0; q < 3; ++q) {
    const int g = q * 256 + j;
    const float base = b_ih[g] + ((q < 2) ? b_hh[g] : 0.f);
    float zd = 0.f, yd = 0.f, y0d = 0.f;
#pragma unroll 8
    for (int u = 0; u < 32; ++u) {
      const float wz = W_ih[g * 96 + 64 + u];
      const float wy = W_ih[g * 96 + 32 + u];
      zd  = fmaf(wz, zs[u], zd);
      yd  = fmaf(wy, bo[u], yd);
      y0d = fmaf(wy, y0[u], y0d);
    }
    cvec [(b * 3 + q) * 256 + j] = base + zd + yd;
    cvec0[(b * 3 + q) * 256 + j] = base + zd + y0d;
  }
}

// ---------------------------------------------------------------------------
// Main persistent GRU. grid 256 (batch), block 512.
// REGISTER STRATEGY (R9): the backend grants arch-VGPR = 65536/T no matter
// what attributes we pass (R1-R8 evidence); at T=512 that is 128. The OTHER
// half of the gfx950 unified file (AGPRs, 256 KB/CU) is reachable only via
// explicit v_accvgpr inline asm with "a" constraints, which the allocator
// must honor. M_z(64) + M_hn(64) = 128 AGPRs/thread; M_r(64)+obs(24)=88 u32
// stay in VGPRs (+~35 live <= 128). 2 waves/SIMD x (128 V + 128 A) = 512 =
// exactly the per-SIMD file. accvgpr_read is volatile so LICM cannot hoist
// 128 loop-invariant reads back into VGPR pressure.
// h_s padded [2][132] -> bank conflicts measured 0 (R6).
// LDS: mxn 131072 | wo 16384 | h 1056 | x 256 | yp 4096 | cv 6144 = 159008 B
// ---------------------------------------------------------------------------
#define LDS_MXN 0
#define LDS_WO  131072
#define LDS_H   147456
#define LDS_X   148512
#define LDS_YP  148768
#define LDS_CV  152864
#define LDS_BYTES 159008

__global__ __launch_bounds__(512, 1) void k_gru(
    const float* __restrict__ obs, const u32* __restrict__ blob,
    const uint4* __restrict__ matsrc,  // = ws+OFF_MXN (mxnL||woL contiguous)
    const float* __restrict__ cvec, const float* __restrict__ cvec0,
    const float* __restrict__ b_hh, const float* __restrict__ b_out,
    float* __restrict__ out) {
  extern __shared__ char smem[];
  uint4* mxn_s = reinterpret_cast<uint4*>(smem + LDS_MXN);  // [16][512]
  uint4* wo_s  = reinterpret_cast<uint4*>(smem + LDS_WO);   // [2][512]
  float* h_s   = reinterpret_cast<float*>(smem + LDS_H);    // [2][132] padded
  float* x_s   = reinterpret_cast<float*>(smem + LDS_X);    // [2][32]
  float* yp_s  = reinterpret_cast<float*>(smem + LDS_YP);   // [2][16][32]
  float* cv_s  = reinterpret_cast<float*>(smem + LDS_CV);   // [2][3][256]

  const int b = blockIdx.x;
  const int tid = threadIdx.x;
  const int j = tid >> 1, s = tid & 1;
  const int o = tid & 31, c = tid >> 5;

  // ---- stage mxnL || woL into LDS (one contiguous 147456-B copy) ----
  {
    uint4* dst = reinterpret_cast<uint4*>(smem);
    for (int i = tid; i < 9216; i += 512) dst[i] = matsrc[i];
  }
  // ---- stage gate constants: cv_s[0]=cvec0 (t==0), cv_s[1]=cvec (t>0) ----
  for (int i = tid; i < 768; i += 512) {
    cv_s[i]       = cvec0[b * 768 + i];
    cv_s[768 + i] = cvec [b * 768 + i];
  }

  // ---- per-thread weights: M_r+obs in VGPRs, M_z+M_hn forced to AGPRs ----
  u32 wb[88];
  u32 az[64], ah[64];
  {
    const uint4* src = reinterpret_cast<const uint4*>(blob + tid * 216);
#pragma unroll
    for (int i = 0; i < 16; ++i) {  // M_r (u32 0..63)
      const uint4 v = src[i];
      wb[4 * i] = v.x; wb[4 * i + 1] = v.y; wb[4 * i + 2] = v.z; wb[4 * i + 3] = v.w;
    }
#pragma unroll
    for (int i = 0; i < 6; ++i) {   // obs (u32 192..215)
      const uint4 v = src[48 + i];
      wb[64 + 4 * i] = v.x; wb[64 + 4 * i + 1] = v.y;
      wb[64 + 4 * i + 2] = v.z; wb[64 + 4 * i + 3] = v.w;
    }
#pragma unroll
    for (int i = 0; i < 16; ++i) {  // M_z (u32 64..127) -> AGPR
      const uint4 v = src[16 + i];
      asm("v_accvgpr_write_b32 %0, %1" : "=a"(az[4 * i + 0]) : "v"(v.x));
      asm("v_accvgpr_write_b32 %0, %1" : "=a"(az[4 * i + 1]) : "v"(v.y));
      asm("v_accvgpr_write_b32 %0, %1" : "=a"(az[4 * i + 2]) : "v"(v.z));
      asm("v_accvgpr_write_b32 %0, %1" : "=a"(az[4 * i + 3]) : "v"(v.w));
    }
#pragma unroll
    for (int i = 0; i < 16; ++i) {  // M_hn (u32 128..191) -> AGPR
      const uint4 v = src[32 + i];
      asm("v_accvgpr_write_b32 %0, %1" : "=a"(ah[4 * i + 0]) : "v"(v.x));
      asm("v_accvgpr_write_b32 %0, %1" : "=a"(ah[4 * i + 1]) : "v"(v.y));
      asm("v_accvgpr_write_b32 %0, %1" : "=a"(ah[4 * i + 2]) : "v"(v.z));
      asm("v_accvgpr_write_b32 %0, %1" : "=a"(ah[4 * i + 3]) : "v"(v.w));
    }
  }

  const float chn = b_hh[512 + j];
  const float bo  = (tid < 32) ? b_out[tid] : 0.f;

  const float* obs_b = obs + (size_t)b * TSTEPS * 32;
  float* out_b = out + (size_t)b * TSTEPS * 32;

  const int hb = 132 * s;  // my padded h slice base (f32 units)

  float hreg = 0.f;
  if (tid < 256) h_s[(tid >> 7) * 132 + (tid & 127)] = 0.f;
  if (tid < 32) x_s[tid] = obs_b[tid];
  __syncthreads();

#pragma unroll 1
  for (int t = 0; t < TSTEPS; ++t) {
    const int cur = t & 1;
    // next-obs prefetch by threads 32..63 (disjoint from y-finalize threads)
    float pf = 0.f;
    if (tid >= 32 && tid < 64) pf = obs_b[(t < TSTEPS - 1 ? t + 1 : t) * 32 + (tid - 32)];

    // gate constants from LDS (issued early; latency hidden under MACs)
    const int tb = (t != 0) ? 768 : 0;
    const float cr  = cv_s[tb + j];
    const float cz  = cv_s[tb + 256 + j];
    const float cxn = cv_s[tb + 512 + j];

    float aR = 0.f, aZ = 0.f, aXN = 0.f, aHN = 0.f;
#pragma unroll
    for (int k = 0; k < 16; ++k) {
      const float4 ha = *reinterpret_cast<const float4*>(&h_s[hb + 8 * k]);
      const float4 hc = *reinterpret_cast<const float4*>(&h_s[hb + 8 * k + 4]);
      const uint4  xw = mxn_s[k * 512 + tid];
      // M_r from VGPRs
      aR  = mac2(aR,  wb[4 * k],     ha.x, ha.y);
      aR  = mac2(aR,  wb[4 * k + 1], ha.z, ha.w);
      aR  = mac2(aR,  wb[4 * k + 2], hc.x, hc.y);
      aR  = mac2(aR,  wb[4 * k + 3], hc.z, hc.w);
      // M_z from AGPRs
      u32 w0, w1, w2, w3;
      asm volatile("v_accvgpr_read_b32 %0, %1" : "=v"(w0) : "a"(az[4 * k + 0]));
      asm volatile("v_accvgpr_read_b32 %0, %1" : "=v"(w1) : "a"(az[4 * k + 1]));
      asm volatile("v_accvgpr_read_b32 %0, %1" : "=v"(w2) : "a"(az[4 * k + 2]));
      asm volatile("v_accvgpr_read_b32 %0, %1" : "=v"(w3) : "a"(az[4 * k + 3]));
      aZ  = mac2(aZ,  w0, ha.x, ha.y);
      aZ  = mac2(aZ,  w1, ha.z, ha.w);
      aZ  = mac2(aZ,  w2, hc.x, hc.y);
      aZ  = mac2(aZ,  w3, hc.z, hc.w);
      // M_hn from AGPRs
      u32 u0, u1, u2, u3;
      asm volatile("v_accvgpr_read_b32 %0, %1" : "=v"(u0) : "a"(ah[4 * k + 0]));
      asm volatile("v_accvgpr_read_b32 %0, %1" : "=v"(u1) : "a"(ah[4 * k + 1]));
      asm volatile("v_accvgpr_read_b32 %0, %1" : "=v"(u2) : "a"(ah[4 * k + 2]));
      asm volatile("v_accvgpr_read_b32 %0, %1" : "=v"(u3) : "a"(ah[4 * k + 3]));
      aHN = mac2(aHN, u0, ha.x, ha.y);
      aHN = mac2(aHN, u1, ha.z, ha.w);
      aHN = mac2(aHN, u2, hc.x, hc.y);
      aHN = mac2(aHN, u3, hc.z, hc.w);
      // M_xn from LDS
      aXN = mac2(aXN, xw.x, ha.x, ha.y);
      aXN = mac2(aXN, xw.y, ha.z, ha.w);
      aXN = mac2(aXN, xw.z, hc.x, hc.y);
      aXN = mac2(aXN, xw.w, hc.z, hc.w);
    }
#pragma unroll
    for (int i = 0; i < 4; ++i) {
      const float4 xv = *reinterpret_cast<const float4*>(&x_s[cur * 32 + 16 * s + 4 * i]);
      aR  = mac2(aR,  wb[64 + 2 * i],     xv.x, xv.y);
      aR  = mac2(aR,  wb[64 + 2 * i + 1], xv.z, xv.w);
      aZ  = mac2(aZ,  wb[72 + 2 * i],     xv.x, xv.y);
      aZ  = mac2(aZ,  wb[72 + 2 * i + 1], xv.z, xv.w);
      aXN = mac2(aXN, wb[80 + 2 * i],     xv.x, xv.y);
      aXN = mac2(aXN, wb[80 + 2 * i + 1], xv.z, xv.w);
    }

    // pair reduction (threads 2j, 2j+1 — same wave)
    aR  += __shfl_xor(aR,  1);
    aZ  += __shfl_xor(aZ,  1);
    aHN += __shfl_xor(aHN, 1);
    aXN += __shfl_xor(aXN, 1);

    const float r    = 1.f / (1.f + __expf(-(cr + aR)));
    const float zg   = 1.f / (1.f + __expf(-(cz + aZ)));
    const float pn   = cxn + aXN + r * (chn + aHN);
    const float n    = 1.f - 2.f / (1.f + __expf(2.f * pn));  // tanh
    const float hnew = fmaf(zg, hreg - n, n);
    hreg = hnew;

    __syncthreads();  // A: all reads of h_s / x_s[cur] done
    if (s == 0) h_s[(j >> 7) * 132 + (j & 127)] = hnew;
    if (tid >= 32 && tid < 64) x_s[(1 - cur) * 32 + (tid - 32)] = pf;
    if (t > 0 && tid < 32) {  // finalize y_{t-1}
      float y = bo;
#pragma unroll
      for (int ww = 0; ww < 16; ++ww) y += yp_s[(1 - cur) * 512 + ww * 32 + tid];
      out_b[(t - 1) * 32 + tid] = y;
    }
    __syncthreads();  // B: new h visible

    // y partials for h_t: thread (o, c) covers h[16c..16c+15]
    {
      const int hy = (c >> 3) * 132 + (c & 7) * 16;
      const float4 h0 = *reinterpret_cast<const float4*>(&h_s[hy]);
      const float4 h1 = *reinterpret_cast<const float4*>(&h_s[hy + 4]);
      const float4 h2 = *reinterpret_cast<const float4*>(&h_s[hy + 8]);
      const float4 h3 = *reinterpret_cast<const float4*>(&h_s[hy + 12]);
      const uint4 w0 = wo_s[tid];
      const uint4 w1 = wo_s[512 + tid];
      float yv = 0.f;
      yv = mac2(yv, w0.x, h0.x, h0.y); yv = mac2(yv, w0.y, h0.z, h0.w);
      yv = mac2(yv, w0.z, h1.x, h1.y); yv = mac2(yv, w0.w, h1.z, h1.w);
      yv = mac2(yv, w1.x, h2.x, h2.y); yv = mac2(yv, w1.y, h2.z, h2.w);
      yv = mac2(yv, w1.z, h3.x, h3.y); yv = mac2(yv, w1.w, h3.z, h3.w);
      yp_s[cur * 512 + c * 32 + o] = yv;
    }
  }

  __syncthreads();
  if (tid < 32) {  // flush y_1023 (t=1023 -> cur=1)
    float y = bo;
#pragma unroll
    for (int ww = 0; ww < 16; ++ww) y += yp_s[512 + ww * 32 + tid];
    out_b[(TSTEPS - 1) * 32 + tid] = y;
  }
}

// ---------------------------------------------------------------------------
extern "C" void kernel_launch(void* const* d_in, const int* in_sizes, int n_in,
                              void* d_out, int out_size, void* d_ws, size_t ws_size,
                              hipStream_t stream) {
  (void)in_sizes; (void)n_in; (void)out_size; (void)ws_size;
  const float* init_y  = (const float*)d_in[0];
  const float* obs_seq = (const float*)d_in[1];
  const float* z_dyn   = (const float*)d_in[2];
  const float* W_ih    = (const float*)d_in[3];
  const float* W_hh    = (const float*)d_in[4];
  const float* b_ih    = (const float*)d_in[5];
  const float* b_hh    = (const float*)d_in[6];
  const float* W_out   = (const float*)d_in[7];
  const float* b_out   = (const float*)d_in[8];
  float* out = (float*)d_out;

  char* ws = (char*)d_ws;
  u32*   blob  = (u32*)(ws + OFF_BLOB);
  uint4* mxnL  = (uint4*)(ws + OFF_MXN);
  uint4* woL   = (uint4*)(ws + OFF_WO);
  float* cvec  = (float*)(ws + OFF_CVEC);
  float* cvec0 = (float*)(ws + OFF_CVEC0);

  hipFuncSetAttribute((const void*)k_gru,
                      hipFuncAttributeMaxDynamicSharedMemorySize, LDS_BYTES);

  k_pack<<<2, 256, 0, stream>>>(W_ih, W_hh, W_out, blob, mxnL, woL);
  k_cvec<<<256, 256, 0, stream>>>(W_ih, b_ih, b_hh, b_out, z_dyn, init_y, cvec, cvec0);
  k_gru<<<BATCH, 512, LDS_BYTES, stream>>>(obs_seq, blob, (const uint4*)(ws + OFF_MXN),
                                           cvec, cvec0, b_hh, b_out, out);
}